// Round 3
// baseline (196.931 us; speedup 1.0000x reference)
//
#include <hip/hip_runtime.h>

#define NPTS 100000
#define P 64
#define C 128
#define CHUNKS 16
#define CHUNK_PTS 6250      // 16 * 6250 = 100000
#define CHUNK_PAD 6400      // padded to multiple of 256

typedef __bf16 bf16_t;
typedef __bf16 bf16x4 __attribute__((ext_vector_type(4)));
typedef __bf16 bf16x8 __attribute__((ext_vector_type(8)));
typedef float floatx4 __attribute__((ext_vector_type(4)));

// Workspace layout (bytes):
//   [0,      65536)    W1t bf16 [256][128]   (s1 folded, transposed: [n][k])
//   [65536, 131072)    W2t bf16 [128][256]   (s2 folded, transposed)
//   [131072,163840)    Wat bf16 [128][128]   (transposed)
//   [163840, +51.2MB)  rec bf16 [NPTS][256]  (a[128] | h2[128] per point)
//   then               partial f32 [64][16][4][128]  (2 MB)

__global__ __launch_bounds__(256) void prep_kernel(
    const float* __restrict__ W1, const float* __restrict__ s1,
    const float* __restrict__ W2, const float* __restrict__ s2,
    const float* __restrict__ Wa,
    bf16_t* __restrict__ W1t, bf16_t* __restrict__ W2t, bf16_t* __restrict__ Wat)
{
  int i0 = blockIdx.x * blockDim.x + threadIdx.x;
  int stride = gridDim.x * blockDim.x;
  for (int i = i0; i < 256 * 128; i += stride) {          // W1t[n][k] = W1[k][n]*s1[n]
    int n = i >> 7, k = i & 127;
    W1t[i] = (bf16_t)(W1[k * 256 + n] * s1[n]);
  }
  for (int i = i0; i < 128 * 256; i += stride) {          // W2t[n][k] = W2[k][n]*s2[n]
    int n = i >> 8, k = i & 255;
    W2t[i] = (bf16_t)(W2[k * 128 + n] * s2[n]);
  }
  for (int i = i0; i < 128 * 128; i += stride) {          // Wat[n][k] = Wa[k][n]
    int n = i >> 7, k = i & 127;
    Wat[i] = (bf16_t)(Wa[k * 128 + n]);
  }
}

// Process one staged 64-point tile: A1 (feature bf16) -> GEMM1 -> Hs -> GEMM2
// -> h2 into A1 -> GEMMa -> aB (overlays Hs) -> logit + rec write.
__device__ __forceinline__ void process_tile(
    bf16_t* A1, bf16_t* Hs, bf16_t* aB,
    const float* w3S, const float* b1S, const float* b2S, float b3v,
    const bf16_t* __restrict__ W1t, const bf16_t* __restrict__ W2t,
    const bf16_t* __restrict__ Wat,
    bf16_t* __restrict__ rec, float* __restrict__ out_logit,
    int m0, int tid, int wave, int lane, int quad, int l16)
{
  const floatx4 zero4 = {0.f, 0.f, 0.f, 0.f};

  // ---- GEMM1: h[64][256] = relu(A1 @ W1' + b1). Wave owns n-cols [wave*64,+64) ----
  {
    floatx4 acc[4][4];
#pragma unroll
    for (int mt = 0; mt < 4; ++mt)
#pragma unroll
      for (int nt = 0; nt < 4; ++nt) acc[mt][nt] = zero4;
#pragma unroll
    for (int kt = 0; kt < 4; ++kt) {
      bf16x8 af[4], bf[4];
#pragma unroll
      for (int mt = 0; mt < 4; ++mt)
        af[mt] = *(const bf16x8*)(A1 + (mt * 16 + l16) * 136 + kt * 32 + quad * 8);
#pragma unroll
      for (int nt = 0; nt < 4; ++nt)
        bf[nt] = *(const bf16x8*)(W1t + (wave * 64 + nt * 16 + l16) * 128 + kt * 32 + quad * 8);
#pragma unroll
      for (int mt = 0; mt < 4; ++mt)
#pragma unroll
        for (int nt = 0; nt < 4; ++nt)
          acc[mt][nt] = __builtin_amdgcn_mfma_f32_16x16x32_bf16(af[mt], bf[nt], acc[mt][nt], 0, 0, 0);
    }
#pragma unroll
    for (int nt = 0; nt < 4; ++nt) {
      int col = wave * 64 + nt * 16 + l16;
      float bias = b1S[col];
#pragma unroll
      for (int mt = 0; mt < 4; ++mt)
#pragma unroll
        for (int r = 0; r < 4; ++r) {
          float hv = fmaxf(acc[mt][nt][r] + bias, 0.f);
          Hs[(mt * 16 + quad * 4 + r) * 264 + col] = (bf16_t)hv;
        }
    }
  }
  __syncthreads();

  // ---- GEMM2: h2[64][128] = relu(h @ W2' + b2) -> bf16 into A1 ----
  {
    floatx4 acc[4][2];
#pragma unroll
    for (int mt = 0; mt < 4; ++mt) { acc[mt][0] = zero4; acc[mt][1] = zero4; }
#pragma unroll
    for (int kt = 0; kt < 8; ++kt) {
      bf16x8 af[4], bf[2];
#pragma unroll
      for (int mt = 0; mt < 4; ++mt)
        af[mt] = *(const bf16x8*)(Hs + (mt * 16 + l16) * 264 + kt * 32 + quad * 8);
#pragma unroll
      for (int nt = 0; nt < 2; ++nt)
        bf[nt] = *(const bf16x8*)(W2t + (wave * 32 + nt * 16 + l16) * 256 + kt * 32 + quad * 8);
#pragma unroll
      for (int mt = 0; mt < 4; ++mt)
#pragma unroll
        for (int nt = 0; nt < 2; ++nt)
          acc[mt][nt] = __builtin_amdgcn_mfma_f32_16x16x32_bf16(af[mt], bf[nt], acc[mt][nt], 0, 0, 0);
    }
#pragma unroll
    for (int nt = 0; nt < 2; ++nt) {
      int col = wave * 32 + nt * 16 + l16;
      float bias = b2S[col];
#pragma unroll
      for (int mt = 0; mt < 4; ++mt)
#pragma unroll
        for (int r = 0; r < 4; ++r) {
          float hv = fmaxf(acc[mt][nt][r] + bias, 0.f);
          A1[(mt * 16 + quad * 4 + r) * 136 + col] = (bf16_t)hv;
        }
    }
  }
  __syncthreads();   // GEMM2 done (Hs reads + A1 h2 writes complete)

  // ---- GEMMa: a[64][128] = h2 @ Wa -> bf16 into aB (overlays Hs, safe now) ----
  {
    floatx4 acc[4][2];
#pragma unroll
    for (int mt = 0; mt < 4; ++mt) { acc[mt][0] = zero4; acc[mt][1] = zero4; }
#pragma unroll
    for (int kt = 0; kt < 4; ++kt) {
      bf16x8 af[4], bf[2];
#pragma unroll
      for (int mt = 0; mt < 4; ++mt)
        af[mt] = *(const bf16x8*)(A1 + (mt * 16 + l16) * 136 + kt * 32 + quad * 8);
#pragma unroll
      for (int nt = 0; nt < 2; ++nt)
        bf[nt] = *(const bf16x8*)(Wat + (wave * 32 + nt * 16 + l16) * 128 + kt * 32 + quad * 8);
#pragma unroll
      for (int mt = 0; mt < 4; ++mt)
#pragma unroll
        for (int nt = 0; nt < 2; ++nt)
          acc[mt][nt] = __builtin_amdgcn_mfma_f32_16x16x32_bf16(af[mt], bf[nt], acc[mt][nt], 0, 0, 0);
    }
#pragma unroll
    for (int nt = 0; nt < 2; ++nt) {
      int col = wave * 32 + nt * 16 + l16;
#pragma unroll
      for (int mt = 0; mt < 4; ++mt)
#pragma unroll
        for (int r = 0; r < 4; ++r)
          aB[(mt * 16 + quad * 4 + r) * 136 + col] = (bf16_t)acc[mt][nt][r];
    }
  }
  __syncthreads();

  // ---- logit: 4 threads/point, vectorized bf16x8 LDS reads ----
  {
    const int m = tid >> 2, g = tid & 3, c0g = g * 32;
    const int mg = m0 + m;
    float lsum = 0.f;
#pragma unroll
    for (int cc = 0; cc < 4; ++cc) {
      bf16x8 v = *(const bf16x8*)(A1 + m * 136 + c0g + cc * 8);
#pragma unroll
      for (int j = 0; j < 8; ++j)
        lsum += (float)v[j] * w3S[c0g + cc * 8 + j];
    }
    lsum += __shfl_xor(lsum, 1);
    lsum += __shfl_xor(lsum, 2);
    if (mg < NPTS && g == 0) out_logit[mg] = lsum + b3v;
  }

  // ---- record write: rec[pt] = {a[0:128], h2[0:128]} bf16, coalesced 8B/lane ----
  for (int i = tid; i < 64 * 64; i += 256) {
    int pt = i >> 6, slot = i & 63;
    if (m0 + pt < NPTS) {
      const bf16_t* src = (slot < 32) ? (aB + pt * 136 + slot * 4)
                                      : (A1 + pt * 136 + (slot - 32) * 4);
      uint2 v = *(const uint2*)src;
      *(uint2*)(rec + (size_t)(m0 + pt) * 256 + slot * 4) = v;
    }
  }
}

// Phase A: 128 points per block, two 64-pt tiles software-pipelined:
// tile1's feature loads are issued before tile0's GEMMs run.
__global__ __launch_bounds__(256) void main_kernel(
    const float* __restrict__ feature,
    const float* __restrict__ b1, const float* __restrict__ b2,
    const float* __restrict__ W3, const float* __restrict__ b3,
    const bf16_t* __restrict__ W1t, const bf16_t* __restrict__ W2t,
    const bf16_t* __restrict__ Wat,
    bf16_t* __restrict__ rec, float* __restrict__ out_logit)
{
  __shared__ __align__(16) char smem[17408 + 33792 + 512 + 1024 + 512];
  bf16_t* A1  = (bf16_t*)smem;
  bf16_t* Hs  = (bf16_t*)(smem + 17408);
  bf16_t* aB  = (bf16_t*)(smem + 17408);          // overlays Hs after GEMM2
  float*  w3S = (float*)(smem + 17408 + 33792);
  float*  b1S = (float*)(smem + 17408 + 33792 + 512);
  float*  b2S = (float*)(smem + 17408 + 33792 + 512 + 1024);

  const int tid  = threadIdx.x;
  const int wave = tid >> 6, lane = tid & 63;
  const int quad = lane >> 4, l16 = lane & 15;
  const int m0 = blockIdx.x * 128;

  if (tid < 128) w3S[tid] = W3[tid];
  if (tid < 128) b2S[tid] = b2[tid];
  b1S[tid] = b1[tid];
  const float b3v = b3[0];

  const int r0 = tid >> 5, c4 = tid & 31;   // staging coords: 8 rows/iter

  // ---- stage tile0 ----
#pragma unroll
  for (int j = 0; j < 8; ++j) {
    int r = r0 + j * 8;
    float4 v = make_float4(0.f, 0.f, 0.f, 0.f);
    if (m0 + r < NPTS) v = *(const float4*)(feature + (size_t)(m0 + r) * C + c4 * 4);
    bf16x4 o = {(bf16_t)v.x, (bf16_t)v.y, (bf16_t)v.z, (bf16_t)v.w};
    *(bf16x4*)(A1 + r * 136 + c4 * 4) = o;
  }
  __syncthreads();

  // ---- prefetch tile1 into registers (waits at conversion, after tile0 work) ----
  float4 f2[8];
#pragma unroll
  for (int j = 0; j < 8; ++j) {
    int r = r0 + j * 8;
    f2[j] = make_float4(0.f, 0.f, 0.f, 0.f);
    if (m0 + 64 + r < NPTS)
      f2[j] = *(const float4*)(feature + (size_t)(m0 + 64 + r) * C + c4 * 4);
  }

  process_tile(A1, Hs, aB, w3S, b1S, b2S, b3v, W1t, W2t, Wat, rec, out_logit,
               m0, tid, wave, lane, quad, l16);
  __syncthreads();   // all epilogue LDS reads done before restaging A1

  // ---- stage tile1 from prefetched registers ----
#pragma unroll
  for (int j = 0; j < 8; ++j) {
    int r = r0 + j * 8;
    bf16x4 o = {(bf16_t)f2[j].x, (bf16_t)f2[j].y, (bf16_t)f2[j].z, (bf16_t)f2[j].w};
    *(bf16x4*)(A1 + r * 136 + c4 * 4) = o;
  }
  __syncthreads();

  process_tile(A1, Hs, aB, w3S, b1S, b2S, b3v, W1t, W2t, Wat, rec, out_logit,
               m0 + 64, tid, wave, lane, quad, l16);
}

// Phase B: 64 planes x 16 chunks. Scan xyz, ballot hits, wave-cooperative
// record load + register accumulation (lane owns channels 2l, 2l+1).
__global__ __launch_bounds__(256) void pool_kernel(
    const float* __restrict__ xyz, const float* __restrict__ out_logit,
    const bf16_t* __restrict__ rec,
    const float* __restrict__ ctr, const float* __restrict__ nrm,
    const float* __restrict__ pmn, const float* __restrict__ pmx,
    float* __restrict__ partial)
{
  const int plane = blockIdx.x >> 4;
  const int chunk = blockIdx.x & 15;
  const int tid = threadIdx.x, lane = tid & 63;

  __shared__ float accS[4][128];   // num_on, den_on, num_off, den_off
  for (int i = tid; i < 512; i += 256) ((float*)accS)[i] = 0.f;

  const float nx = nrm[plane * 3], ny = nrm[plane * 3 + 1], nz = nrm[plane * 3 + 2];
  const float offs = ctr[plane * 3] * nx + ctr[plane * 3 + 1] * ny + ctr[plane * 3 + 2] * nz;
  const float mnx = pmn[plane * 3], mny = pmn[plane * 3 + 1];
  const float mxx = pmx[plane * 3], mxy = pmx[plane * 3 + 1];
  __syncthreads();

  const int base = chunk * CHUNK_PTS;
  float nOn0 = 0, nOn1 = 0, dOn0 = 0, dOn1 = 0;
  float nOf0 = 0, nOf1 = 0, dOf0 = 0, dOf1 = 0;

  for (int i = tid; i < CHUNK_PAD; i += 256) {
    int pt = base + i;
    bool hit = false;
    if (i < CHUNK_PTS) {
      float x = xyz[pt * 3], y = xyz[pt * 3 + 1], z = xyz[pt * 3 + 2];
      float proj = x * nx + y * ny + z * nz;
      hit = (fabsf(proj - offs) < 0.1f) &&
            (x >= mnx) && (x < mxx) && (y >= mny) && (y < mxy);
    }
    unsigned long long m = __ballot(hit);
    while (m) {
      int l = __builtin_ctzll(m);
      m &= m - 1;
      int hpt = __shfl(pt, l);
      float lg = out_logit[hpt];                       // broadcast load
      const unsigned* r32 = (const unsigned*)(rec + (size_t)hpt * 256);
      unsigned ap = r32[lane];
      unsigned hp = r32[64 + lane];
      float a0 = __uint_as_float(ap << 16);
      float a1 = __uint_as_float(ap & 0xffff0000u);
      float h0 = __uint_as_float(hp << 16);
      float h1 = __uint_as_float(hp & 0xffff0000u);
      float e0 = __expf(a0), e1 = __expf(a1);
      if (lg > 0.f) { nOn0 += e0 * h0; nOn1 += e1 * h1; dOn0 += e0; dOn1 += e1; }
      else          { nOf0 += e0 * h0; nOf1 += e1 * h1; dOf0 += e0; dOf1 += e1; }
    }
  }

  atomicAdd(&accS[0][lane * 2],     nOn0);
  atomicAdd(&accS[0][lane * 2 + 1], nOn1);
  atomicAdd(&accS[1][lane * 2],     dOn0);
  atomicAdd(&accS[1][lane * 2 + 1], dOn1);
  atomicAdd(&accS[2][lane * 2],     nOf0);
  atomicAdd(&accS[2][lane * 2 + 1], nOf1);
  atomicAdd(&accS[3][lane * 2],     dOf0);
  atomicAdd(&accS[3][lane * 2 + 1], dOf1);
  __syncthreads();

  float* dst = partial + (size_t)blockIdx.x * 512;
  for (int i = tid; i < 512; i += 256) dst[i] = ((float*)accS)[i];
}

// Finalize: 256 threads per (sel,plane): chunk-sum split 2 ways, matvec
// reduction split 2 ways, LDS combine.
__global__ __launch_bounds__(256) void finalize_kernel(
    const float* __restrict__ partial,
    const float* __restrict__ Wm, const float* __restrict__ bm,
    const float* __restrict__ ctr, const float* __restrict__ nrm,
    const float* __restrict__ pmn, const float* __restrict__ pmx,
    float* __restrict__ out)
{
  int sel = blockIdx.x >> 6, p = blockIdx.x & 63;
  int tid = threadIdx.x, j = tid & 127, half = tid >> 7;
  __shared__ float numS[2][128], denS[2][128], aggS[128], sumS[2][128];

  const float* bp = partial + ((size_t)p * 16 + half * 8) * 512 + sel * 256;
  float num = 0.f, den = 0.f;
#pragma unroll
  for (int k = 0; k < 8; ++k) {
    num += bp[k * 512 + j];
    den += bp[k * 512 + 128 + j];
  }
  numS[half][j] = num;
  denS[half][j] = den;
  __syncthreads();
  if (tid < 128)
    aggS[tid] = (numS[0][tid] + numS[1][tid]) / (denS[0][tid] + denS[1][tid] + 1e-9f);
  __syncthreads();

  float s = 0.f;
  const int cbase = half * 64;
#pragma unroll 8
  for (int c = 0; c < 64; ++c)
    s += aggS[cbase + c] * Wm[(cbase + c) * C + j];
  sumS[half][j] = s;
  __syncthreads();

  float* dst = out + NPTS + sel * (P * 140) + p * 140;
  if (tid < 128)
    dst[tid] = fmaxf(sumS[0][tid] + sumS[1][tid] + bm[tid], 0.f);
  if (tid < 12) {
    float v;
    if (tid < 3)      v = ctr[p * 3 + tid];
    else if (tid < 6) v = nrm[p * 3 + tid - 3];
    else if (tid < 9) v = pmn[p * 3 + tid - 6];
    else              v = pmx[p * 3 + tid - 9];
    dst[C + tid] = v;
  }
}

extern "C" void kernel_launch(void* const* d_in, const int* in_sizes, int n_in,
                              void* d_out, int out_size, void* d_ws, size_t ws_size,
                              hipStream_t stream)
{
  const float* feature = (const float*)d_in[0];
  const float* xyz     = (const float*)d_in[1];
  const float* ctr     = (const float*)d_in[2];
  const float* nrm     = (const float*)d_in[3];
  const float* pmn     = (const float*)d_in[4];
  const float* pmx     = (const float*)d_in[5];
  const float* W1      = (const float*)d_in[6];
  const float* s1      = (const float*)d_in[7];
  const float* b1      = (const float*)d_in[8];
  const float* W2      = (const float*)d_in[9];
  const float* s2      = (const float*)d_in[10];
  const float* b2      = (const float*)d_in[11];
  const float* W3      = (const float*)d_in[12];
  const float* b3      = (const float*)d_in[13];
  const float* Wa      = (const float*)d_in[14];
  const float* Wm      = (const float*)d_in[15];
  const float* bm      = (const float*)d_in[16];
  float* out = (float*)d_out;

  char* ws = (char*)d_ws;
  bf16_t* W1t = (bf16_t*)(ws);
  bf16_t* W2t = (bf16_t*)(ws + 65536);
  bf16_t* Wat = (bf16_t*)(ws + 131072);
  bf16_t* rec = (bf16_t*)(ws + 163840);                       // NPTS*512 B
  float* partial = (float*)(ws + 163840 + (size_t)NPTS * 512); // 1024*512 f32

  prep_kernel<<<64, 256, 0, stream>>>(W1, s1, W2, s2, Wa, W1t, W2t, Wat);
  main_kernel<<<(NPTS + 127) / 128, 256, 0, stream>>>(
      feature, b1, b2, W3, b3, W1t, W2t, Wat, rec, out);
  pool_kernel<<<64 * CHUNKS, 256, 0, stream>>>(
      xyz, out, rec, ctr, nrm, pmn, pmx, partial);
  finalize_kernel<<<128, 256, 0, stream>>>(partial, Wm, bm, ctr, nrm, pmn, pmx, out);
}